// Round 8
// baseline (679.572 us; speedup 1.0000x reference)
//
#include <hip/hip_runtime.h>
#include <hip/hip_bf16.h>

#define N_NODES 50000
#define N_EDGES 800000
#define EN_EDGES (N_EDGES + N_NODES)   // with self-loops
#define IN_F 128
#define H_F 64
#define BN_EPS 1e-5f
#define POOL_NB 256                    // k_pool blocks (head fused via atomic)

__device__ __forceinline__ unsigned short f2bf(float f) {
    __hip_bfloat16 b = __float2bfloat16(f);
    unsigned short u;
    __builtin_memcpy(&u, &b, 2);
    return u;
}
__device__ __forceinline__ float bf2f(unsigned short u) {
    __hip_bfloat16 b;
    __builtin_memcpy(&b, &u, 2);
    return __bfloat162float(b);
}

// ---------------- CSR build ----------------

__global__ void k_init(int* __restrict__ cursor, int* __restrict__ counter) {
    int i = blockIdx.x * 256 + threadIdx.x;
    if (i < N_NODES) cursor[i] = 1;        // self-loop pre-count
    if (i == 0) *counter = 0;              // pool-completion counter
}

__global__ void k_hist(const int* __restrict__ dst, int* __restrict__ cursor) {
    int e = blockIdx.x * 256 + threadIdx.x;
    if (e < N_EDGES) atomicAdd(&cursor[dst[e]], 1);
}

// Single-block scan over 50000 counts: thread t owns 49 contiguous entries.
__global__ __launch_bounds__(1024) void k_scan(int* __restrict__ cntcur,
                                               int* __restrict__ offsets) {
    __shared__ int ws[1024];
    int t = threadIdx.x;
    int base = t * 49;
    int c[49];
    int sum = 0;
    #pragma unroll
    for (int i = 0; i < 49; i++) {
        int idx = base + i;
        c[i] = (idx < N_NODES) ? cntcur[idx] : 0;
        sum += c[i];
    }
    ws[t] = sum; __syncthreads();
    for (int d = 1; d < 1024; d <<= 1) {
        int v = (t >= d) ? ws[t - d] : 0;
        __syncthreads();
        ws[t] += v;
        __syncthreads();
    }
    int run = ws[t] - sum;                 // exclusive prefix
    #pragma unroll
    for (int i = 0; i < 49; i++) {
        int idx = base + i;
        if (idx < N_NODES) { offsets[idx] = run; cntcur[idx] = run; run += c[i]; }
    }
    if (t == 1023) offsets[N_NODES] = ws[1023];
}

// ssrc stored as ushort (src < 50000 < 65536): halves random-store line churn.
__global__ void k_scatter(const int* __restrict__ src, const int* __restrict__ dst,
                          int* __restrict__ cursor, unsigned short* __restrict__ ssrc) {
    int e = blockIdx.x * 256 + threadIdx.x;
    if (e >= EN_EDGES) return;
    int s, d;
    if (e < N_EDGES) { s = src[e]; d = dst[e]; }
    else { s = e - N_EDGES; d = s; }
    int pos = atomicAdd(&cursor[d], 1);
    ssrc[pos] = (unsigned short)s;
}

// ---------------- Layer 1 GEMM: row-per-lane, scalar W loads ----------------
__global__ __launch_bounds__(256) void k_gemm1(
        const float* __restrict__ x, const float* __restrict__ W,
        const float* __restrict__ a_s, const float* __restrict__ a_d,
        unsigned short* __restrict__ hb, float* __restrict__ asn, float* __restrict__ adn) {
    __shared__ float Xs[64 * 129];     // +1 pad, conflict-free
    __shared__ float asb[4][64], adb[4][64];
    int t = threadIdx.x, lane = t & 63, wave = t >> 6;
    int row0 = blockIdx.x * 64;
    for (int i = t; i < 64 * IN_F; i += 256) {
        int r = i >> 7, c = i & 127;
        Xs[r * 129 + c] = (row0 + r < N_NODES) ? x[(size_t)(row0 + r) * IN_F + c] : 0.f;
    }
    __syncthreads();
    int jb = __builtin_amdgcn_readfirstlane(wave << 4);   // uniform col base -> s_load W
    float acc[16];
    #pragma unroll
    for (int j = 0; j < 16; j++) acc[j] = 0.f;
    for (int k0 = 0; k0 < IN_F; k0 += 8) {
        float xr[8];
        #pragma unroll
        for (int kk = 0; kk < 8; kk++) xr[kk] = Xs[lane * 129 + k0 + kk];
        #pragma unroll
        for (int kk = 0; kk < 8; kk++) {
            const float* wr = W + (k0 + kk) * H_F + jb;
            #pragma unroll
            for (int j = 0; j < 16; j++) acc[j] = fmaf(xr[kk], wr[j], acc[j]);
        }
    }
    int row = row0 + lane;
    float pa = 0.f, pd = 0.f;
    #pragma unroll
    for (int j = 0; j < 16; j++) { pa += acc[j] * a_s[jb + j]; pd += acc[j] * a_d[jb + j]; }
    asb[wave][lane] = pa; adb[wave][lane] = pd;
    if (row < N_NODES) {
        uint4 pk[2];
        unsigned int* pw = (unsigned int*)pk;
        #pragma unroll
        for (int q = 0; q < 8; q++)
            pw[q] = (unsigned int)f2bf(acc[2*q]) | ((unsigned int)f2bf(acc[2*q+1]) << 16);
        uint4* hp = (uint4*)(hb + (size_t)row * H_F + jb);
        hp[0] = pk[0]; hp[1] = pk[1];
    }
    __syncthreads();
    if (wave == 0 && row < N_NODES) {
        asn[row] = asb[0][lane] + asb[1][lane] + asb[2][lane] + asb[3][lane];
        adn[row] = adb[0][lane] + adb[1][lane] + adb[2][lane] + adb[3][lane];
    }
}

// ---------------- Layers 2-5 GEMM: K=64, fused proj ----------------
__global__ __launch_bounds__(256) void k_gemm(
        const float* __restrict__ xp, const float* __restrict__ W,
        const float* __restrict__ PW, const float* __restrict__ pbias,
        const float* __restrict__ a_s, const float* __restrict__ a_d,
        unsigned short* __restrict__ hb, float* __restrict__ p,
        float* __restrict__ asn, float* __restrict__ adn) {
    __shared__ float Xs[64 * 65];      // +1 pad, conflict-free
    __shared__ float asb[4][64], adb[4][64];
    int t = threadIdx.x, lane = t & 63, wave = t >> 6;
    int row0 = blockIdx.x * 64;
    for (int i = t; i < 64 * H_F; i += 256) {
        int r = i >> 6, c = i & 63;
        Xs[r * 65 + c] = (row0 + r < N_NODES) ? xp[(size_t)(row0 + r) * H_F + c] : 0.f;
    }
    __syncthreads();
    int jb = __builtin_amdgcn_readfirstlane(wave << 4);
    float acc[16], pac[16];
    #pragma unroll
    for (int j = 0; j < 16; j++) { acc[j] = 0.f; pac[j] = 0.f; }
    for (int k0 = 0; k0 < H_F; k0 += 8) {
        float xr[8];
        #pragma unroll
        for (int kk = 0; kk < 8; kk++) xr[kk] = Xs[lane * 65 + k0 + kk];
        #pragma unroll
        for (int kk = 0; kk < 8; kk++) {
            const float* wr = W  + (k0 + kk) * H_F + jb;
            const float* pr = PW + (k0 + kk) * H_F + jb;
            #pragma unroll
            for (int j = 0; j < 16; j++) {
                acc[j] = fmaf(xr[kk], wr[j], acc[j]);
                pac[j] = fmaf(xr[kk], pr[j], pac[j]);
            }
        }
    }
    int row = row0 + lane;
    float pa = 0.f, pd = 0.f;
    #pragma unroll
    for (int j = 0; j < 16; j++) { pa += acc[j] * a_s[jb + j]; pd += acc[j] * a_d[jb + j]; }
    asb[wave][lane] = pa; adb[wave][lane] = pd;
    if (row < N_NODES) {
        uint4 pk[2];
        unsigned int* pw = (unsigned int*)pk;
        #pragma unroll
        for (int q = 0; q < 8; q++)
            pw[q] = (unsigned int)f2bf(acc[2*q]) | ((unsigned int)f2bf(acc[2*q+1]) << 16);
        uint4* hp = (uint4*)(hb + (size_t)row * H_F + jb);
        hp[0] = pk[0]; hp[1] = pk[1];
        float4* pp = (float4*)(p + (size_t)row * H_F + jb);
        #pragma unroll
        for (int q = 0; q < 4; q++)
            pp[q] = make_float4(pac[4*q] + pbias[jb+4*q],   pac[4*q+1] + pbias[jb+4*q+1],
                                pac[4*q+2] + pbias[jb+4*q+2], pac[4*q+3] + pbias[jb+4*q+3]);
    }
    __syncthreads();
    if (wave == 0 && row < N_NODES) {
        asn[row] = asb[0][lane] + asb[1][lane] + asb[2][lane] + asb[3][lane];
        adn[row] = adb[0][lane] + adb[1][lane] + adb[2][lane] + adb[3][lane];
    }
}

// ---------------- Fused attention softmax + aggregation ----------------
// Wave per dst. Pass 1: lane-strided online softmax. Pass 2: wave-uniform
// serial gather, manually unrolled 8-wide: packed-ssrc dwords -> 8 independent
// s_load asn -> 8 independent bf16 gathers in flight.
template <bool HAS_RES>
__global__ __launch_bounds__(256) void k_attn_aggr(
        const unsigned short* __restrict__ hb,
        const float* __restrict__ asn, const float* __restrict__ adn,
        const int* __restrict__ offsets, const unsigned short* __restrict__ ssrc,
        const float* __restrict__ bias,
        const float* __restrict__ bg, const float* __restrict__ bb,
        const float* __restrict__ bm, const float* __restrict__ bv,
        const float* __restrict__ res, float* __restrict__ out) {
    int t = threadIdx.x, lane = t & 63, wave = t >> 6;
    int d = blockIdx.x * 4 + wave;
    if (d >= N_NODES) return;
    int du  = __builtin_amdgcn_readfirstlane(d);
    int beg = __builtin_amdgcn_readfirstlane(offsets[du]);
    int end = __builtin_amdgcn_readfirstlane(offsets[du + 1]);
    float add = adn[du];

    // pass 1: online softmax stats (lane-strided; <=1 iter for deg<=64)
    float m = -1e30f, ssum = 0.f;
    for (int j = beg + lane; j < end; j += 64) {
        float e = asn[(int)ssrc[j]] + add;
        e = e < 0.f ? 0.2f * e : e;
        float nm = fmaxf(m, e);
        ssum = ssum * __expf(m - nm) + __expf(e - nm);
        m = nm;
    }
    #pragma unroll
    for (int dlt = 32; dlt > 0; dlt >>= 1) {
        float m2 = __shfl_xor(m, dlt);
        float s2 = __shfl_xor(ssum, dlt);
        float nm = fmaxf(m, m2);
        ssum = ssum * __expf(m - nm) + s2 * __expf(m2 - nm);
        m = nm;
    }
    float inv = 1.f / ssum;   // self-loop -> ssum > 0

    // pass 2: 8-wide unrolled wave-uniform gather
    float acc = 0.f;
    int e = beg;
    if ((e & 1) && e < end) {              // align to dword boundary
        int s = (int)ssrc[e];
        float ev = asn[s] + add;
        ev = ev < 0.f ? 0.2f * ev : ev;
        acc = fmaf(__expf(ev - m) * inv, bf2f(hb[(size_t)s * H_F + lane]), acc);
        e++;
    }
    const unsigned int* ss32 = (const unsigned int*)ssrc;
    for (; e + 8 <= end; e += 8) {
        unsigned int p0 = ss32[(e >> 1) + 0], p1 = ss32[(e >> 1) + 1];
        unsigned int p2 = ss32[(e >> 1) + 2], p3 = ss32[(e >> 1) + 3];
        int s0 = p0 & 0xffff, s1 = p0 >> 16, s2 = p1 & 0xffff, s3 = p1 >> 16;
        int s4 = p2 & 0xffff, s5 = p2 >> 16, s6 = p3 & 0xffff, s7 = p3 >> 16;
        float e0 = asn[s0], e1 = asn[s1], e2 = asn[s2], e3 = asn[s3];
        float e4 = asn[s4], e5 = asn[s5], e6 = asn[s6], e7 = asn[s7];
        float h0 = bf2f(hb[(size_t)s0 * H_F + lane]);
        float h1 = bf2f(hb[(size_t)s1 * H_F + lane]);
        float h2 = bf2f(hb[(size_t)s2 * H_F + lane]);
        float h3 = bf2f(hb[(size_t)s3 * H_F + lane]);
        float h4 = bf2f(hb[(size_t)s4 * H_F + lane]);
        float h5 = bf2f(hb[(size_t)s5 * H_F + lane]);
        float h6 = bf2f(hb[(size_t)s6 * H_F + lane]);
        float h7 = bf2f(hb[(size_t)s7 * H_F + lane]);
        e0 += add; e1 += add; e2 += add; e3 += add;
        e4 += add; e5 += add; e6 += add; e7 += add;
        e0 = e0 < 0.f ? 0.2f * e0 : e0;  e1 = e1 < 0.f ? 0.2f * e1 : e1;
        e2 = e2 < 0.f ? 0.2f * e2 : e2;  e3 = e3 < 0.f ? 0.2f * e3 : e3;
        e4 = e4 < 0.f ? 0.2f * e4 : e4;  e5 = e5 < 0.f ? 0.2f * e5 : e5;
        e6 = e6 < 0.f ? 0.2f * e6 : e6;  e7 = e7 < 0.f ? 0.2f * e7 : e7;
        acc = fmaf(__expf(e0 - m) * inv, h0, acc);
        acc = fmaf(__expf(e1 - m) * inv, h1, acc);
        acc = fmaf(__expf(e2 - m) * inv, h2, acc);
        acc = fmaf(__expf(e3 - m) * inv, h3, acc);
        acc = fmaf(__expf(e4 - m) * inv, h4, acc);
        acc = fmaf(__expf(e5 - m) * inv, h5, acc);
        acc = fmaf(__expf(e6 - m) * inv, h6, acc);
        acc = fmaf(__expf(e7 - m) * inv, h7, acc);
    }
    for (; e < end; e++) {
        int s = (int)ssrc[e];
        float ev = asn[s] + add;
        ev = ev < 0.f ? 0.2f * ev : ev;
        acc = fmaf(__expf(ev - m) * inv, bf2f(hb[(size_t)s * H_F + lane]), acc);
    }

    float v = acc + bias[lane];
    v = fmaxf(v, 0.f);
    v = (v - bm[lane]) * rsqrtf(bv[lane] + BN_EPS) * bg[lane] + bb[lane];
    if (HAS_RES) v += res[(size_t)d * H_F + lane];
    out[(size_t)d * H_F + lane] = v;
}

// ---------------- Mean pool + head (fused: last block runs the MLP) ----------------
__global__ __launch_bounds__(256) void k_pool(
        const float* __restrict__ x, float* __restrict__ partials, int* __restrict__ counter,
        const float* __restrict__ hW1, const float* __restrict__ hb1,
        const float* __restrict__ hg, const float* __restrict__ hbb,
        const float* __restrict__ hm, const float* __restrict__ hv,
        const float* __restrict__ hW2, const float* __restrict__ hb2,
        float* __restrict__ out) {
    __shared__ float red[256 * 4];
    int t = threadIdx.x, b = blockIdx.x;
    const float4* xv = (const float4*)x;
    const int total = N_NODES * (H_F / 4);          // 800000 float4s
    float a0 = 0.f, a1 = 0.f, a2 = 0.f, a3 = 0.f;
    for (int i = b * 256 + t; i < total; i += POOL_NB * 256) {
        float4 v = xv[i];
        a0 += v.x; a1 += v.y; a2 += v.z; a3 += v.w;
    }
    red[t * 4 + 0] = a0; red[t * 4 + 1] = a1; red[t * 4 + 2] = a2; red[t * 4 + 3] = a3;
    __syncthreads();
    if (t < 64) {
        int p = t >> 2, q = t & 3;                  // feature = p*4 + q = t
        float s = 0.f;
        #pragma unroll
        for (int k = 0; k < 16; k++) s += red[(p + 16 * k) * 4 + q];
        partials[b * H_F + t] = s;
    }
    __threadfence();
    __shared__ int is_last;
    __syncthreads();                                // partials store complete
    if (t == 0) is_last = (atomicAdd(counter, 1) == POOL_NB - 1);
    __syncthreads();
    if (!is_last) return;

    // final reduce + MLP head (single block)
    __shared__ float red2[256];
    __shared__ float gl[64];
    __shared__ float h1[32];
    int f = t & 63, g = t >> 6;
    float s = 0.f;
    for (int k = g; k < POOL_NB; k += 4) s += partials[k * H_F + f];
    red2[t] = s;
    __syncthreads();
    if (t < 64) gl[t] = (red2[t] + red2[64 + t] + red2[128 + t] + red2[192 + t]) * (1.f / N_NODES);
    __syncthreads();
    if (t < 32) {
        float v = hb1[t];
        for (int l = 0; l < 64; l++) v += gl[l] * hW1[l * 32 + t];
        v = fmaxf(v, 0.f);
        v = (v - hm[t]) * rsqrtf(hv[t] + BN_EPS) * hg[t] + hbb[t];
        h1[t] = v;
    }
    __syncthreads();
    if (t == 0) {
        float v = hb2[0];
        for (int j = 0; j < 32; j++) v += h1[j] * hW2[j];
        out[0] = v;
    }
}

// ---------------- Launch ----------------

extern "C" void kernel_launch(void* const* d_in, const int* in_sizes, int n_in,
                              void* d_out, int out_size, void* d_ws, size_t ws_size,
                              hipStream_t stream) {
    (void)in_sizes; (void)n_in; (void)out_size; (void)ws_size;
    const float* x        = (const float*)d_in[0];
    const int*   ei       = (const int*)d_in[1];
    const float* conv1_W  = (const float*)d_in[2];
    const float* conv1_as = (const float*)d_in[3];
    const float* conv1_ad = (const float*)d_in[4];
    const float* conv1_b  = (const float*)d_in[5];
    const float* convW    = (const float*)d_in[6];
    const float* conv_as  = (const float*)d_in[7];
    const float* conv_ad  = (const float*)d_in[8];
    const float* conv_b   = (const float*)d_in[9];
    const float* bn_g     = (const float*)d_in[10];
    const float* bn_b     = (const float*)d_in[11];
    const float* bn_m     = (const float*)d_in[12];
    const float* bn_v     = (const float*)d_in[13];
    const float* projW    = (const float*)d_in[14];
    const float* projb    = (const float*)d_in[15];
    const float* hW1      = (const float*)d_in[16];
    const float* hb1      = (const float*)d_in[17];
    const float* hbn_g    = (const float*)d_in[18];
    const float* hbn_b    = (const float*)d_in[19];
    const float* hbn_m    = (const float*)d_in[20];
    const float* hbn_v    = (const float*)d_in[21];
    const float* hW2      = (const float*)d_in[22];
    const float* hb2      = (const float*)d_in[23];

    const int* e_src = ei;
    const int* e_dst = ei + N_EDGES;

    char* wsb = (char*)d_ws;
    size_t cur = 0;
    auto alloc = [&](size_t bytes) -> void* {
        void* p = wsb + cur;
        cur = (cur + bytes + 255) & ~(size_t)255;
        return p;
    };
    int*            offsets  = (int*)alloc((N_NODES + 1) * sizeof(int));
    int*            cursor   = (int*)alloc(N_NODES * sizeof(int));
    unsigned short* ssrc     = (unsigned short*)alloc(EN_EDGES * sizeof(unsigned short));
    int*            counter  = (int*)alloc(sizeof(int));
    unsigned short* hbuf     = (unsigned short*)alloc((size_t)N_NODES * H_F * sizeof(unsigned short));
    float*          p        = (float*)alloc((size_t)N_NODES * H_F * sizeof(float));
    float*          asn      = (float*)alloc(N_NODES * sizeof(float));
    float*          adn      = (float*)alloc(N_NODES * sizeof(float));
    float*          xa       = (float*)alloc((size_t)N_NODES * H_F * sizeof(float));
    float*          xb       = (float*)alloc((size_t)N_NODES * H_F * sizeof(float));
    float*          partials = (float*)alloc(POOL_NB * H_F * sizeof(float));

    // CSR build (graph identical for all layers)
    k_init<<<dim3((N_NODES + 255) / 256), dim3(256), 0, stream>>>(cursor, counter);
    k_hist<<<dim3((N_EDGES + 255) / 256), dim3(256), 0, stream>>>(e_dst, cursor);
    k_scan<<<dim3(1), dim3(1024), 0, stream>>>(cursor, offsets);
    k_scatter<<<dim3((EN_EDGES + 255) / 256), dim3(256), 0, stream>>>(e_src, e_dst, cursor, ssrc);

    dim3 blk(256);
    dim3 gemm_grid((N_NODES + 63) / 64);
    dim3 aggr_grid((N_NODES + 3) / 4);

    // Layer 1
    k_gemm1<<<gemm_grid, blk, 0, stream>>>(x, conv1_W, conv1_as, conv1_ad, hbuf, asn, adn);
    k_attn_aggr<false><<<aggr_grid, blk, 0, stream>>>(hbuf, asn, adn, offsets, ssrc, conv1_b,
                                                      bn_g, bn_b, bn_m, bn_v, nullptr, xa);

    // Layers 2-5
    float* bufs[2] = { xa, xb };
    for (int l = 0; l < 4; l++) {
        float* in  = bufs[l & 1];
        float* out = bufs[(l + 1) & 1];
        k_gemm<<<gemm_grid, blk, 0, stream>>>(in, convW + (size_t)l * H_F * H_F,
                                              projW + (size_t)l * H_F * H_F, projb + l * H_F,
                                              conv_as + l * H_F, conv_ad + l * H_F,
                                              hbuf, p, asn, adn);
        k_attn_aggr<true><<<aggr_grid, blk, 0, stream>>>(hbuf, asn, adn, offsets, ssrc,
                                                         conv_b + l * H_F,
                                                         bn_g + (l + 1) * H_F, bn_b + (l + 1) * H_F,
                                                         bn_m + (l + 1) * H_F, bn_v + (l + 1) * H_F,
                                                         p, out);
    }

    // Pool + fused head (after 4 residual layers the final activations are in xa)
    k_pool<<<dim3(POOL_NB), blk, 0, stream>>>(xa, partials, counter,
                                              hW1, hb1, hbn_g, hbn_b, hbn_m, hbn_v,
                                              hW2, hb2, (float*)d_out);
}

// Round 9
// 576.515 us; speedup vs baseline: 1.1788x; 1.1788x over previous
//
#include <hip/hip_runtime.h>
#include <hip/hip_bf16.h>

#define N_NODES 50000
#define N_EDGES 800000
#define EN_EDGES (N_EDGES + N_NODES)   // with self-loops
#define IN_F 128
#define H_F 64
#define BN_EPS 1e-5f
#define SCAN_NB 49                     // ceil(50000/1024)
#define POOL_NB 256                    // k_pool blocks (head fused via atomic)

__device__ __forceinline__ unsigned short f2bf(float f) {
    __hip_bfloat16 b = __float2bfloat16(f);
    unsigned short u;
    __builtin_memcpy(&u, &b, 2);
    return u;
}
__device__ __forceinline__ float bf2f(unsigned short u) {
    __hip_bfloat16 b;
    __builtin_memcpy(&b, &u, 2);
    return __bfloat162float(b);
}

// ---------------- CSR build ----------------

__global__ void k_init(int* __restrict__ cursor, int* __restrict__ counter) {
    int i = blockIdx.x * 256 + threadIdx.x;
    if (i < N_NODES) cursor[i] = 1;        // self-loop pre-count
    if (i == 0) *counter = 0;              // pool-completion counter
}

__global__ void k_hist(const int* __restrict__ dst, int* __restrict__ cursor) {
    int e = blockIdx.x * 256 + threadIdx.x;
    if (e < N_EDGES) atomicAdd(&cursor[dst[e]], 1);
}

__global__ void k_scan_bsum(const int* __restrict__ cnt, int* __restrict__ bsum) {
    __shared__ int sd[256];
    int b = blockIdx.x, t = threadIdx.x;
    int base = b * 1024;
    int s = 0;
    for (int i = t; i < 1024; i += 256) {
        int idx = base + i;
        if (idx < N_NODES) s += cnt[idx];
    }
    sd[t] = s; __syncthreads();
    for (int d = 128; d > 0; d >>= 1) {
        if (t < d) sd[t] += sd[t + d];
        __syncthreads();
    }
    if (t == 0) bsum[b] = sd[0];
}

__global__ void k_scan_small(int* __restrict__ bsum, int* __restrict__ offsets) {
    if (threadIdx.x == 0 && blockIdx.x == 0) {
        int run = 0;
        for (int i = 0; i < SCAN_NB; i++) { int v = bsum[i]; bsum[i] = run; run += v; }
        offsets[N_NODES] = run;
    }
}

// cntcur read as counts, overwritten with start offsets (same index -> safe)
__global__ void k_scan_final(int* __restrict__ cntcur, const int* __restrict__ bsum,
                             int* __restrict__ offsets) {
    __shared__ int ls[256];
    int b = blockIdx.x, t = threadIdx.x;
    int i0 = b * 1024 + t * 4;
    int c0 = 0, c1 = 0, c2 = 0, c3 = 0;
    if (i0 + 0 < N_NODES) c0 = cntcur[i0 + 0];
    if (i0 + 1 < N_NODES) c1 = cntcur[i0 + 1];
    if (i0 + 2 < N_NODES) c2 = cntcur[i0 + 2];
    if (i0 + 3 < N_NODES) c3 = cntcur[i0 + 3];
    int tsum = c0 + c1 + c2 + c3;
    ls[t] = tsum; __syncthreads();
    for (int d = 1; d < 256; d <<= 1) {
        int v = (t >= d) ? ls[t - d] : 0;
        __syncthreads();
        ls[t] += v;
        __syncthreads();
    }
    int tex = ls[t] - tsum;               // exclusive prefix within block
    int base = bsum[b] + tex;
    if (i0 + 0 < N_NODES) { offsets[i0 + 0] = base; cntcur[i0 + 0] = base; base += c0; }
    if (i0 + 1 < N_NODES) { offsets[i0 + 1] = base; cntcur[i0 + 1] = base; base += c1; }
    if (i0 + 2 < N_NODES) { offsets[i0 + 2] = base; cntcur[i0 + 2] = base; base += c2; }
    if (i0 + 3 < N_NODES) { offsets[i0 + 3] = base; cntcur[i0 + 3] = base; base += c3; }
}

// ssrc stored as ushort (src < 50000 < 65536)
__global__ void k_scatter(const int* __restrict__ src, const int* __restrict__ dst,
                          int* __restrict__ cursor, unsigned short* __restrict__ ssrc) {
    int e = blockIdx.x * 256 + threadIdx.x;
    if (e >= EN_EDGES) return;
    int s, d;
    if (e < N_EDGES) { s = src[e]; d = dst[e]; }
    else { s = e - N_EDGES; d = s; }
    int pos = atomicAdd(&cursor[d], 1);
    ssrc[pos] = (unsigned short)s;
}

// ---------------- Layer 1 GEMM: row-per-lane, scalar W loads ----------------
__global__ __launch_bounds__(256) void k_gemm1(
        const float* __restrict__ x, const float* __restrict__ W,
        const float* __restrict__ a_s, const float* __restrict__ a_d,
        unsigned short* __restrict__ hb, float* __restrict__ asn, float* __restrict__ adn) {
    __shared__ float Xs[64 * 129];     // +1 pad, conflict-free
    __shared__ float asb[4][64], adb[4][64];
    int t = threadIdx.x, lane = t & 63, wave = t >> 6;
    int row0 = blockIdx.x * 64;
    for (int i = t; i < 64 * IN_F; i += 256) {
        int r = i >> 7, c = i & 127;
        Xs[r * 129 + c] = (row0 + r < N_NODES) ? x[(size_t)(row0 + r) * IN_F + c] : 0.f;
    }
    __syncthreads();
    int jb = __builtin_amdgcn_readfirstlane(wave << 4);   // uniform col base -> s_load W
    float acc[16];
    #pragma unroll
    for (int j = 0; j < 16; j++) acc[j] = 0.f;
    for (int k0 = 0; k0 < IN_F; k0 += 8) {
        float xr[8];
        #pragma unroll
        for (int kk = 0; kk < 8; kk++) xr[kk] = Xs[lane * 129 + k0 + kk];
        #pragma unroll
        for (int kk = 0; kk < 8; kk++) {
            const float* wr = W + (k0 + kk) * H_F + jb;
            #pragma unroll
            for (int j = 0; j < 16; j++) acc[j] = fmaf(xr[kk], wr[j], acc[j]);
        }
    }
    int row = row0 + lane;
    float pa = 0.f, pd = 0.f;
    #pragma unroll
    for (int j = 0; j < 16; j++) { pa += acc[j] * a_s[jb + j]; pd += acc[j] * a_d[jb + j]; }
    asb[wave][lane] = pa; adb[wave][lane] = pd;
    if (row < N_NODES) {
        uint4 pk[2];
        unsigned int* pw = (unsigned int*)pk;
        #pragma unroll
        for (int q = 0; q < 8; q++)
            pw[q] = (unsigned int)f2bf(acc[2*q]) | ((unsigned int)f2bf(acc[2*q+1]) << 16);
        uint4* hp = (uint4*)(hb + (size_t)row * H_F + jb);
        hp[0] = pk[0]; hp[1] = pk[1];
    }
    __syncthreads();
    if (wave == 0 && row < N_NODES) {
        asn[row] = asb[0][lane] + asb[1][lane] + asb[2][lane] + asb[3][lane];
        adn[row] = adb[0][lane] + adb[1][lane] + adb[2][lane] + adb[3][lane];
    }
}

// ---------------- Layers 2-5 GEMM: K=64, fused proj ----------------
__global__ __launch_bounds__(256) void k_gemm(
        const float* __restrict__ xp, const float* __restrict__ W,
        const float* __restrict__ PW, const float* __restrict__ pbias,
        const float* __restrict__ a_s, const float* __restrict__ a_d,
        unsigned short* __restrict__ hb, float* __restrict__ p,
        float* __restrict__ asn, float* __restrict__ adn) {
    __shared__ float Xs[64 * 65];      // +1 pad, conflict-free
    __shared__ float asb[4][64], adb[4][64];
    int t = threadIdx.x, lane = t & 63, wave = t >> 6;
    int row0 = blockIdx.x * 64;
    for (int i = t; i < 64 * H_F; i += 256) {
        int r = i >> 6, c = i & 63;
        Xs[r * 65 + c] = (row0 + r < N_NODES) ? xp[(size_t)(row0 + r) * H_F + c] : 0.f;
    }
    __syncthreads();
    int jb = __builtin_amdgcn_readfirstlane(wave << 4);
    float acc[16], pac[16];
    #pragma unroll
    for (int j = 0; j < 16; j++) { acc[j] = 0.f; pac[j] = 0.f; }
    for (int k0 = 0; k0 < H_F; k0 += 8) {
        float xr[8];
        #pragma unroll
        for (int kk = 0; kk < 8; kk++) xr[kk] = Xs[lane * 65 + k0 + kk];
        #pragma unroll
        for (int kk = 0; kk < 8; kk++) {
            const float* wr = W  + (k0 + kk) * H_F + jb;
            const float* pr = PW + (k0 + kk) * H_F + jb;
            #pragma unroll
            for (int j = 0; j < 16; j++) {
                acc[j] = fmaf(xr[kk], wr[j], acc[j]);
                pac[j] = fmaf(xr[kk], pr[j], pac[j]);
            }
        }
    }
    int row = row0 + lane;
    float pa = 0.f, pd = 0.f;
    #pragma unroll
    for (int j = 0; j < 16; j++) { pa += acc[j] * a_s[jb + j]; pd += acc[j] * a_d[jb + j]; }
    asb[wave][lane] = pa; adb[wave][lane] = pd;
    if (row < N_NODES) {
        uint4 pk[2];
        unsigned int* pw = (unsigned int*)pk;
        #pragma unroll
        for (int q = 0; q < 8; q++)
            pw[q] = (unsigned int)f2bf(acc[2*q]) | ((unsigned int)f2bf(acc[2*q+1]) << 16);
        uint4* hp = (uint4*)(hb + (size_t)row * H_F + jb);
        hp[0] = pk[0]; hp[1] = pk[1];
        float4* pp = (float4*)(p + (size_t)row * H_F + jb);
        #pragma unroll
        for (int q = 0; q < 4; q++)
            pp[q] = make_float4(pac[4*q] + pbias[jb+4*q],   pac[4*q+1] + pbias[jb+4*q+1],
                                pac[4*q+2] + pbias[jb+4*q+2], pac[4*q+3] + pbias[jb+4*q+3]);
    }
    __syncthreads();
    if (wave == 0 && row < N_NODES) {
        asn[row] = asb[0][lane] + asb[1][lane] + asb[2][lane] + asb[3][lane];
        adn[row] = adb[0][lane] + adb[1][lane] + adb[2][lane] + adb[3][lane];
    }
}

// ---------------- Fused attention softmax + aggregation ----------------
// Wave per dst. Fast path deg<=64 (virtually always): pass 1 computes per-lane
// alpha wave-parallel and stashes it in LDS; pass 2 is the proven serial
// wave-uniform gather reading alpha via LDS broadcast (no per-edge exp/asn).
template <bool HAS_RES>
__global__ __launch_bounds__(256) void k_attn_aggr(
        const unsigned short* __restrict__ hb,
        const float* __restrict__ asn, const float* __restrict__ adn,
        const int* __restrict__ offsets, const unsigned short* __restrict__ ssrc,
        const float* __restrict__ bias,
        const float* __restrict__ bg, const float* __restrict__ bb,
        const float* __restrict__ bm, const float* __restrict__ bv,
        const float* __restrict__ res, float* __restrict__ out) {
    __shared__ float al_lds[4][64];
    int t = threadIdx.x, lane = t & 63, wave = t >> 6;
    int d = blockIdx.x * 4 + wave;
    if (d >= N_NODES) return;
    int du  = __builtin_amdgcn_readfirstlane(d);
    int beg = __builtin_amdgcn_readfirstlane(offsets[du]);
    int end = __builtin_amdgcn_readfirstlane(offsets[du + 1]);
    int deg = end - beg;
    float add = adn[du];
    float acc = 0.f;

    if (deg <= 64) {
        // pass 1: wave-parallel softmax, alpha -> LDS
        bool act = lane < deg;
        float ev = -1e30f;
        if (act) {
            int si = (int)ssrc[beg + lane];
            ev = asn[si] + add;
            ev = ev < 0.f ? 0.2f * ev : ev;
        }
        float m = ev;
        #pragma unroll
        for (int dlt = 32; dlt > 0; dlt >>= 1) m = fmaxf(m, __shfl_xor(m, dlt));
        float ex = act ? __expf(ev - m) : 0.f;
        float ss = ex;
        #pragma unroll
        for (int dlt = 32; dlt > 0; dlt >>= 1) ss += __shfl_xor(ss, dlt);
        al_lds[wave][lane] = ex / ss;          // self-loop -> ss >= 1

        // pass 2: serial wave-uniform gather; alpha via LDS broadcast
        int j = 0;
        if ((beg & 1) && j < deg) {            // align packed ssrc reads
            int s = (int)ssrc[beg];
            acc = fmaf(al_lds[wave][0], bf2f(hb[(size_t)s * H_F + lane]), acc);
            j = 1;
        }
        const unsigned int* ss32 = (const unsigned int*)ssrc;
        for (; j + 8 <= deg; j += 8) {
            int e = beg + j;
            unsigned int p0 = ss32[(e >> 1) + 0], p1 = ss32[(e >> 1) + 1];
            unsigned int p2 = ss32[(e >> 1) + 2], p3 = ss32[(e >> 1) + 3];
            int s0 = p0 & 0xffff, s1 = p0 >> 16, s2 = p1 & 0xffff, s3 = p1 >> 16;
            int s4 = p2 & 0xffff, s5 = p2 >> 16, s6 = p3 & 0xffff, s7 = p3 >> 16;
            float h0 = bf2f(hb[(size_t)s0 * H_F + lane]);
            float h1 = bf2f(hb[(size_t)s1 * H_F + lane]);
            float h2 = bf2f(hb[(size_t)s2 * H_F + lane]);
            float h3 = bf2f(hb[(size_t)s3 * H_F + lane]);
            float h4 = bf2f(hb[(size_t)s4 * H_F + lane]);
            float h5 = bf2f(hb[(size_t)s5 * H_F + lane]);
            float h6 = bf2f(hb[(size_t)s6 * H_F + lane]);
            float h7 = bf2f(hb[(size_t)s7 * H_F + lane]);
            acc = fmaf(al_lds[wave][j + 0], h0, acc);
            acc = fmaf(al_lds[wave][j + 1], h1, acc);
            acc = fmaf(al_lds[wave][j + 2], h2, acc);
            acc = fmaf(al_lds[wave][j + 3], h3, acc);
            acc = fmaf(al_lds[wave][j + 4], h4, acc);
            acc = fmaf(al_lds[wave][j + 5], h5, acc);
            acc = fmaf(al_lds[wave][j + 6], h6, acc);
            acc = fmaf(al_lds[wave][j + 7], h7, acc);
        }
        for (; j < deg; j++) {
            int s = (int)ssrc[beg + j];
            acc = fmaf(al_lds[wave][j], bf2f(hb[(size_t)s * H_F + lane]), acc);
        }
    } else {
        // generic two-pass fallback (statistically never for this graph)
        float m = -1e30f, ssum = 0.f;
        for (int j = beg + lane; j < end; j += 64) {
            float e = asn[(int)ssrc[j]] + add;
            e = e < 0.f ? 0.2f * e : e;
            float nm = fmaxf(m, e);
            ssum = ssum * __expf(m - nm) + __expf(e - nm);
            m = nm;
        }
        #pragma unroll
        for (int dlt = 32; dlt > 0; dlt >>= 1) {
            float m2 = __shfl_xor(m, dlt);
            float s2 = __shfl_xor(ssum, dlt);
            float nm = fmaxf(m, m2);
            ssum = ssum * __expf(m - nm) + s2 * __expf(m2 - nm);
            m = nm;
        }
        float inv = 1.f / ssum;
        for (int e = beg; e < end; e++) {
            int s = (int)ssrc[e];
            float ev = asn[s] + add;
            ev = ev < 0.f ? 0.2f * ev : ev;
            acc = fmaf(__expf(ev - m) * inv, bf2f(hb[(size_t)s * H_F + lane]), acc);
        }
    }

    float v = acc + bias[lane];
    v = fmaxf(v, 0.f);
    v = (v - bm[lane]) * rsqrtf(bv[lane] + BN_EPS) * bg[lane] + bb[lane];
    if (HAS_RES) v += res[(size_t)d * H_F + lane];
    out[(size_t)d * H_F + lane] = v;
}

// ---------------- Mean pool + head (fused: last block runs the MLP) ----------------
__global__ __launch_bounds__(256) void k_pool(
        const float* __restrict__ x, float* __restrict__ partials, int* __restrict__ counter,
        const float* __restrict__ hW1, const float* __restrict__ hb1,
        const float* __restrict__ hg, const float* __restrict__ hbb,
        const float* __restrict__ hm, const float* __restrict__ hv,
        const float* __restrict__ hW2, const float* __restrict__ hb2,
        float* __restrict__ out) {
    __shared__ float red[256 * 4];
    int t = threadIdx.x, b = blockIdx.x;
    const float4* xv = (const float4*)x;
    const int total = N_NODES * (H_F / 4);          // 800000 float4s
    float a0 = 0.f, a1 = 0.f, a2 = 0.f, a3 = 0.f;
    for (int i = b * 256 + t; i < total; i += POOL_NB * 256) {
        float4 v = xv[i];
        a0 += v.x; a1 += v.y; a2 += v.z; a3 += v.w;
    }
    red[t * 4 + 0] = a0; red[t * 4 + 1] = a1; red[t * 4 + 2] = a2; red[t * 4 + 3] = a3;
    __syncthreads();
    if (t < 64) {
        int p = t >> 2, q = t & 3;                  // feature = p*4 + q = t
        float s = 0.f;
        #pragma unroll
        for (int k = 0; k < 16; k++) s += red[(p + 16 * k) * 4 + q];
        partials[b * H_F + t] = s;
    }
    __threadfence();
    __shared__ int is_last;
    __syncthreads();                                // partials store complete
    if (t == 0) is_last = (atomicAdd(counter, 1) == POOL_NB - 1);
    __syncthreads();
    if (!is_last) return;

    // final reduce + MLP head (single block)
    __shared__ float red2[256];
    __shared__ float gl[64];
    __shared__ float h1[32];
    int f = t & 63, g = t >> 6;
    float s = 0.f;
    for (int k = g; k < POOL_NB; k += 4) s += partials[k * H_F + f];
    red2[t] = s;
    __syncthreads();
    if (t < 64) gl[t] = (red2[t] + red2[64 + t] + red2[128 + t] + red2[192 + t]) * (1.f / N_NODES);
    __syncthreads();
    if (t < 32) {
        float v = hb1[t];
        for (int l = 0; l < 64; l++) v += gl[l] * hW1[l * 32 + t];
        v = fmaxf(v, 0.f);
        v = (v - hm[t]) * rsqrtf(hv[t] + BN_EPS) * hg[t] + hbb[t];
        h1[t] = v;
    }
    __syncthreads();
    if (t == 0) {
        float v = hb2[0];
        for (int j = 0; j < 32; j++) v += h1[j] * hW2[j];
        out[0] = v;
    }
}

// ---------------- Launch ----------------

extern "C" void kernel_launch(void* const* d_in, const int* in_sizes, int n_in,
                              void* d_out, int out_size, void* d_ws, size_t ws_size,
                              hipStream_t stream) {
    (void)in_sizes; (void)n_in; (void)out_size; (void)ws_size;
    const float* x        = (const float*)d_in[0];
    const int*   ei       = (const int*)d_in[1];
    const float* conv1_W  = (const float*)d_in[2];
    const float* conv1_as = (const float*)d_in[3];
    const float* conv1_ad = (const float*)d_in[4];
    const float* conv1_b  = (const float*)d_in[5];
    const float* convW    = (const float*)d_in[6];
    const float* conv_as  = (const float*)d_in[7];
    const float* conv_ad  = (const float*)d_in[8];
    const float* conv_b   = (const float*)d_in[9];
    const float* bn_g     = (const float*)d_in[10];
    const float* bn_b     = (const float*)d_in[11];
    const float* bn_m     = (const float*)d_in[12];
    const float* bn_v     = (const float*)d_in[13];
    const float* projW    = (const float*)d_in[14];
    const float* projb    = (const float*)d_in[15];
    const float* hW1      = (const float*)d_in[16];
    const float* hb1      = (const float*)d_in[17];
    const float* hbn_g    = (const float*)d_in[18];
    const float* hbn_b    = (const float*)d_in[19];
    const float* hbn_m    = (const float*)d_in[20];
    const float* hbn_v    = (const float*)d_in[21];
    const float* hW2      = (const float*)d_in[22];
    const float* hb2      = (const float*)d_in[23];

    const int* e_src = ei;
    const int* e_dst = ei + N_EDGES;

    char* wsb = (char*)d_ws;
    size_t cur = 0;
    auto alloc = [&](size_t bytes) -> void* {
        void* p = wsb + cur;
        cur = (cur + bytes + 255) & ~(size_t)255;
        return p;
    };
    int*            offsets  = (int*)alloc((N_NODES + 1) * sizeof(int));
    int*            cursor   = (int*)alloc(N_NODES * sizeof(int));
    unsigned short* ssrc     = (unsigned short*)alloc(EN_EDGES * sizeof(unsigned short));
    int*            bsum     = (int*)alloc(64 * sizeof(int));
    int*            counter  = (int*)alloc(sizeof(int));
    unsigned short* hbuf     = (unsigned short*)alloc((size_t)N_NODES * H_F * sizeof(unsigned short));
    float*          p        = (float*)alloc((size_t)N_NODES * H_F * sizeof(float));
    float*          asn      = (float*)alloc(N_NODES * sizeof(float));
    float*          adn      = (float*)alloc(N_NODES * sizeof(float));
    float*          xa       = (float*)alloc((size_t)N_NODES * H_F * sizeof(float));
    float*          xb       = (float*)alloc((size_t)N_NODES * H_F * sizeof(float));
    float*          partials = (float*)alloc(POOL_NB * H_F * sizeof(float));

    // CSR build (graph identical for all layers)
    k_init<<<dim3((N_NODES + 255) / 256), dim3(256), 0, stream>>>(cursor, counter);
    k_hist<<<dim3((N_EDGES + 255) / 256), dim3(256), 0, stream>>>(e_dst, cursor);
    k_scan_bsum<<<dim3(SCAN_NB), dim3(256), 0, stream>>>(cursor, bsum);
    k_scan_small<<<dim3(1), dim3(64), 0, stream>>>(bsum, offsets);
    k_scan_final<<<dim3(SCAN_NB), dim3(256), 0, stream>>>(cursor, bsum, offsets);
    k_scatter<<<dim3((EN_EDGES + 255) / 256), dim3(256), 0, stream>>>(e_src, e_dst, cursor, ssrc);

    dim3 blk(256);
    dim3 gemm_grid((N_NODES + 63) / 64);
    dim3 aggr_grid((N_NODES + 3) / 4);

    // Layer 1
    k_gemm1<<<gemm_grid, blk, 0, stream>>>(x, conv1_W, conv1_as, conv1_ad, hbuf, asn, adn);
    k_attn_aggr<false><<<aggr_grid, blk, 0, stream>>>(hbuf, asn, adn, offsets, ssrc, conv1_b,
                                                      bn_g, bn_b, bn_m, bn_v, nullptr, xa);

    // Layers 2-5
    float* bufs[2] = { xa, xb };
    for (int l = 0; l < 4; l++) {
        float* in  = bufs[l & 1];
        float* out = bufs[(l + 1) & 1];
        k_gemm<<<gemm_grid, blk, 0, stream>>>(in, convW + (size_t)l * H_F * H_F,
                                              projW + (size_t)l * H_F * H_F, projb + l * H_F,
                                              conv_as + l * H_F, conv_ad + l * H_F,
                                              hbuf, p, asn, adn);
        k_attn_aggr<true><<<aggr_grid, blk, 0, stream>>>(hbuf, asn, adn, offsets, ssrc,
                                                         conv_b + l * H_F,
                                                         bn_g + (l + 1) * H_F, bn_b + (l + 1) * H_F,
                                                         bn_m + (l + 1) * H_F, bn_v + (l + 1) * H_F,
                                                         p, out);
    }

    // Pool + fused head (after 4 residual layers the final activations are in xa)
    k_pool<<<dim3(POOL_NB), blk, 0, stream>>>(xa, partials, counter,
                                              hW1, hb1, hbn_g, hbn_b, hbn_m, hbn_v,
                                              hW2, hb2, (float*)d_out);
}